// Round 4
// baseline (440.731 us; speedup 1.0000x reference)
//
#include <hip/hip_runtime.h>
#include <hip/hip_bf16.h>
#include <math.h>

// Problem constants (match reference)
#define T_TOK 1024
#define H_DIM 1024
#define I_DIM 512
#define E_NUM 32
#define K_TOP 4
#define G_NUM 8
#define TG_NUM 4
#define CAP 256              // C = 2*T*K/E
#define IS_DIM 1024          // I * NS
#define RSCALE 2.5f

#define MAXTILES 36          // 4 shared (256-row) + <=32 routed (one per expert)

// ws layout (byte offsets)
#define WS_CNT_OFF    0          // int cnt[32]
#define WS_NT_OFF     128        // int ntiles
#define WS_TILE_OFF   256        // int tiles[MAXTILES][4] = (e, r0, ne, boff)
#define WS_EIDX_OFF   4096       // int eidx[T*K]
#define WS_WN_OFF     20480      // float wnorm[T*K]
#define WS_STOK_OFF   36864      // int slot_token[E*CAP]
#define WS_SW_OFF     69632      // float slot_w[E*CAP]
#define WS_ACT_OFF    102400     // bf16 act[E*CAP*I]  (8 MB)
#define WS_ACTS_OFF   (102400 + (size_t)E_NUM*CAP*I_DIM*2)   // bf16 acts[T*IS] (2 MB)
#define WS_XB_OFF     (WS_ACTS_OFF + (size_t)T_TOK*IS_DIM*2) // bf16 xb[T*H]    (2 MB)
#define WS_T2S_OFF    (WS_XB_OFF + (size_t)T_TOK*H_DIM*2)    // int tok2slot[T*K] (16 KB)
#define WS_YR_OFF     (WS_T2S_OFF + (size_t)T_TOK*K_TOP*4)   // f32 yr[T*K][H] (16 MB)

typedef __attribute__((ext_vector_type(8))) short short8v;
typedef __attribute__((ext_vector_type(4))) float f32x4;
typedef __attribute__((ext_vector_type(4))) unsigned uint4v;

__device__ __forceinline__ short f2bf(float f) {          // RNE, epilogue only
    unsigned u = __float_as_uint(f);
    u += 0x7FFFu + ((u >> 16) & 1u);
    return (short)(u >> 16);
}
// pack 2 floats -> 2 bf16 (round-half-up): 3 VALU ops
__device__ __forceinline__ unsigned pk2bf(float a, float b) {
    unsigned ua = __float_as_uint(a) + 0x8000u;
    unsigned ub = __float_as_uint(b) + 0x8000u;
    return __builtin_amdgcn_perm(ub, ua, 0x07060302);      // lo short=bf(a), hi=bf(b)
}
__device__ __forceinline__ uint4v pk8bf(float4 lo, float4 hi) {
    uint4v r; r.x = pk2bf(lo.x, lo.y); r.y = pk2bf(lo.z, lo.w);
    r.z = pk2bf(hi.x, hi.y); r.w = pk2bf(hi.z, hi.w); return r;
}
__device__ __forceinline__ float silu_(float g) { return g / (1.f + expf(-g)); }

// Relaxed barrier: LDS-drain only, NO vmcnt(0) — in-flight global loads for the
// next K-step survive the barrier (counted vmcnt lands at next iter's ds_write).
// This is the m97-structure fix: don't drain the prefetch queue at the barrier.
#define BAR_RELAXED() do { \
    asm volatile("s_waitcnt lgkmcnt(0)" ::: "memory"); \
    __builtin_amdgcn_s_barrier(); \
    asm volatile("" ::: "memory"); \
} while (0)

#define LDSTRIDE 40   // shorts per LDS row (80 B, keeps b128 writes aligned)

// -------- gating (also emits bf16 copy of x for GEMM A-operand) --------
__global__ __launch_bounds__(256) void gate_kernel(
    const float* __restrict__ x, const float* __restrict__ gate_w,
    const float* __restrict__ e_bias,
    int* __restrict__ eidx, float* __restrict__ wnorm, short* __restrict__ xb)
{
    __shared__ float xs[H_DIM];
    __shared__ float logits[E_NUM];
    const int t = blockIdx.x;
    const int tid = threadIdx.x;
    float4 v = ((const float4*)(x + (size_t)t * H_DIM))[tid];
    ((float4*)xs)[tid] = v;
    {   // bf16 copy of this token's row (same rounding as GEMM staging uses)
        unsigned* xd = (unsigned*)(xb + (size_t)t * H_DIM) + tid * 2;
        xd[0] = pk2bf(v.x, v.y); xd[1] = pk2bf(v.z, v.w);
    }
    __syncthreads();

    const int e = tid >> 3, sub = tid & 7;   // 32 experts x 8 threads
    const float4* gw4 = (const float4*)(gate_w + (size_t)e * H_DIM + sub * 128);
    const float4* xr4 = (const float4*)(xs + sub * 128);
    float p = 0.f;
    #pragma unroll
    for (int h = 0; h < 32; ++h) {
        float4 a = xr4[h], b = gw4[h];
        p += a.x * b.x + a.y * b.y + a.z * b.z + a.w * b.w;
    }
    for (int off = 4; off; off >>= 1) p += __shfl_down(p, off, 8);
    if (sub == 0) logits[e] = p;
    __syncthreads();
    if (tid != 0) return;

    float sc[E_NUM], sfc[E_NUM];
    for (int i = 0; i < E_NUM; ++i) {
        sc[i] = 1.f / (1.f + expf(-logits[i]));
        sfc[i] = sc[i] + e_bias[i];
    }
    float gs[G_NUM];
    for (int g = 0; g < G_NUM; ++g) {
        float m1 = -1e30f, m2 = -1e30f;
        for (int j = 0; j < E_NUM / G_NUM; ++j) {
            float v2 = sfc[g * (E_NUM / G_NUM) + j];
            if (v2 > m1) { m2 = m1; m1 = v2; } else if (v2 > m2) m2 = v2;
        }
        gs[g] = m1 + m2;
    }
    bool gm[G_NUM];
    for (int g = 0; g < G_NUM; ++g) gm[g] = false;
    for (int it = 0; it < TG_NUM; ++it) {
        int best = -1; float bv = -1e30f;
        for (int g = 0; g < G_NUM; ++g) if (!gm[g] && gs[g] > bv) { bv = gs[g]; best = g; }
        gm[best] = true;
    }
    float sm[E_NUM];
    for (int i = 0; i < E_NUM; ++i) sm[i] = gm[i / (E_NUM / G_NUM)] ? sfc[i] : 0.0f;
    int idx[K_TOP]; float w[K_TOP]; float tsum = 0.f;
    for (int it = 0; it < K_TOP; ++it) {
        int best = 0; float bv = -1e30f;
        for (int i = 0; i < E_NUM; ++i) if (sm[i] > bv) { bv = sm[i]; best = i; }
        sm[best] = -1e30f;
        idx[it] = best; w[it] = sc[best]; tsum += w[it];
    }
    float inv = RSCALE / (tsum + 1e-20f);
    const int base = t * K_TOP;
    for (int it = 0; it < K_TOP; ++it) {
        eidx[base + it] = idx[it];
        wnorm[base + it] = w[it] * inv;
    }
}

// ---- deterministic capacity dispatch + tile list + compact slot mapping ----
__global__ __launch_bounds__(256) void assign_kernel(
    const int* __restrict__ eidx, const float* __restrict__ wnorm,
    int* __restrict__ cnt, int* __restrict__ slot_token, float* __restrict__ slot_w,
    int* __restrict__ ntiles, int* __restrict__ tiles, int* __restrict__ tok2slot)
{
    __shared__ int   se[T_TOK * K_TOP];
    __shared__ float swt[T_TOK * K_TOP];
    __shared__ int   scnt[E_NUM];
    const int tid = threadIdx.x;
    for (int i = tid; i < T_TOK * K_TOP; i += 256) { se[i] = eidx[i]; swt[i] = wnorm[i]; }
    __syncthreads();

    const int e = tid >> 3;
    const int seg = tid & 7;
    const int base = seg * 512;
    int c = 0;
    for (int i = 0; i < 512; ++i) c += (se[base + i] == e);
    int excl = 0, total = 0;
    for (int s = 0; s < 8; ++s) {
        int cs = __shfl(c, s, 8);
        total += cs;
        if (s < seg) excl += cs;
    }
    if (seg == 0) { cnt[e] = total; scnt[e] = total; }
    __syncthreads();
    // compact base offset for this expert (sum of kept counts of lower experts)
    int boff = 0;
    for (int ee = 0; ee < e; ++ee) boff += min(scnt[ee], CAP);

    int pos = excl;
    for (int i = 0; i < 512; ++i) {
        if (se[base + i] == e) {
            const int g = base + i;
            if (pos < CAP) {
                slot_token[e * CAP + pos] = g >> 2;
                slot_w[e * CAP + pos] = swt[g];
                tok2slot[g] = boff + pos;
            } else {
                tok2slot[g] = -1;   // capacity-dropped (matches reference keep=0)
            }
            ++pos;
        }
    }
    __syncthreads();
    if (tid == 0) {
        int nt = 0;
        // shared-expert tiles first (heaviest -> dispatched first)
        for (int t0 = 0; t0 < T_TOK; t0 += 256) {
            tiles[nt * 4] = -1; tiles[nt * 4 + 1] = t0; tiles[nt * 4 + 2] = 256;
            tiles[nt * 4 + 3] = 0; ++nt;
        }
        // one tile per routed expert (<=256 rows, wave-chunked in-kernel)
        int off = 0;
        for (int ee = 0; ee < E_NUM; ++ee) {
            int n = min(scnt[ee], CAP);
            if (n > 0) {
                tiles[nt * 4] = ee; tiles[nt * 4 + 1] = 0; tiles[nt * 4 + 2] = n;
                tiles[nt * 4 + 3] = off; ++nt;
            }
            off += n;
        }
        *ntiles = nt;
    }
}

// ---------------- MFMA GEMM: block tile 256(M, chunked) x 128(B-rows), BK=32 ----
// 512 threads = 8 waves: wm=wid&3 owns M-chunk wm (64 rows), wn=wid>>2 owns 64 B-rows.
// B panel is read exactly ONCE per (tile, col-block).
// In-loop barrier is BAR_RELAXED (no vmcnt drain): next-step prefetch loads stay
// in flight through the barrier and the MFMA phase.

// gate_up + SiLU*mul for routed (+slot_w) AND shared experts. grid (16, MAXTILES)
__global__ __launch_bounds__(512, 2) void gu_all_kernel(
    const short* __restrict__ xb, const float* __restrict__ w_gate_up,
    const float* __restrict__ w_gus,
    const int* __restrict__ ntiles, const int* __restrict__ tiles,
    const int* __restrict__ slot_token, const float* __restrict__ slot_w,
    short* __restrict__ act, short* __restrict__ acts)
{
    if ((int)blockIdx.y >= *ntiles) return;
    const int e  = tiles[blockIdx.y * 4];
    const int r0 = tiles[blockIdx.y * 4 + 1];
    const int ne = tiles[blockIdx.y * 4 + 2];
    const bool sh = (e < 0);
    if (!sh && blockIdx.x >= I_DIM / 64) return;
    const int col0 = blockIdx.x * 64;
    const int mchunks = (ne + 63) >> 6;        // 1..4 chunks of 64 rows
    const int rows = mchunks << 6;

    __shared__ __align__(16) short As[2][256 * LDSTRIDE];
    __shared__ __align__(16) short Bs[2][128 * LDSTRIDE];
    __shared__ int   toks[256];
    __shared__ float sws[256];

    const int tid = threadIdx.x;
    const int lane = tid & 63, wid = tid >> 6;
    const int wm = wid & 3, wn = wid >> 2;
    const int lr16 = lane & 15, kc = lane >> 4;
    const int sc_ = tid & 3, srow = tid >> 2;  // staging: 8-elem chunk, row 0..127

    if (tid < 256) {
        if (sh) { toks[tid] = r0 + tid; sws[tid] = 1.f; }
        else {
            bool v = tid < ne;
            toks[tid] = v ? slot_token[e * CAP + tid] : 0;
            sws[tid]  = v ? slot_w[e * CAP + tid] : 0.f;
        }
    }
    __syncthreads();

    const int IDim = sh ? IS_DIM : I_DIM;
    const float* wbase = sh ? w_gus : (w_gate_up + (size_t)e * (2 * I_DIM) * H_DIM);
    // B-row c -> weight row: 16-row groups alternate gate/up so acc pairs line up
    const int wr = ((srow >> 4) & 1) * IDim + col0 + ((srow >> 5) << 4) + (srow & 15);
    const float* bptr = wbase + (size_t)wr * H_DIM + sc_ * 8;
    const bool a0v = srow < rows;
    const bool a1v = (srow + 128) < rows;
    const short* aptr0 = xb + (size_t)toks[srow] * H_DIM + sc_ * 8;
    const short* aptr1 = xb + (size_t)toks[srow + 128] * H_DIM + sc_ * 8;
    const int aoff0 = srow * LDSTRIDE + sc_ * 8;
    const int aoff1 = (srow + 128) * LDSTRIDE + sc_ * 8;
    const int boff  = srow * LDSTRIDE + sc_ * 8;

    f32x4 acc[4][4];
    #pragma unroll
    for (int i = 0; i < 4; ++i)
        #pragma unroll
        for (int j = 0; j < 4; ++j) acc[i][j] = 0.f;

    short8v cA0{}, cA1{};
    if (a0v) cA0 = *(const short8v*)(aptr0);
    if (a1v) cA1 = *(const short8v*)(aptr1);
    float4 cB0 = *(const float4*)(bptr), cB1 = *(const float4*)(bptr + 4);

    int buf = 0;
    for (int k0 = 0; k0 < H_DIM; k0 += 32) {
        short8v nA0{}, nA1{};
        float4 nB0{}, nB1{};
        const int k1 = k0 + 32;
        if (k1 < H_DIM) {
            if (a0v) nA0 = *(const short8v*)(aptr0 + k1);
            if (a1v) nA1 = *(const short8v*)(aptr1 + k1);
            nB0 = *(const float4*)(bptr + k1); nB1 = *(const float4*)(bptr + k1 + 4);
        }
        if (a0v) *(short8v*)&As[buf][aoff0] = cA0;
        if (a1v) *(short8v*)&As[buf][aoff1] = cA1;
        *(uint4v*)&Bs[buf][boff] = pk8bf(cB0, cB1);
        BAR_RELAXED();
        if (wm < mchunks) {
            short8v a_[4], b_[4];
            #pragma unroll
            for (int mt = 0; mt < 4; ++mt)
                a_[mt] = *(const short8v*)&As[buf][(wm * 64 + mt * 16 + lr16) * LDSTRIDE + kc * 8];
            #pragma unroll
            for (int nt = 0; nt < 4; ++nt)
                b_[nt] = *(const short8v*)&Bs[buf][(wn * 64 + nt * 16 + lr16) * LDSTRIDE + kc * 8];
            #pragma unroll
            for (int mt = 0; mt < 4; ++mt)
                #pragma unroll
                for (int nt = 0; nt < 4; ++nt)
                    acc[mt][nt] = __builtin_amdgcn_mfma_f32_16x16x32_bf16(a_[mt], b_[nt], acc[mt][nt], 0, 0, 0);
        }
        buf ^= 1;
        cA0 = nA0; cA1 = nA1; cB0 = nB0; cB1 = nB1;
    }

    if (wm >= mchunks) return;
    #pragma unroll
    for (int mt = 0; mt < 4; ++mt) {
        #pragma unroll
        for (int q = 0; q < 2; ++q) {
            f32x4 g = acc[mt][2 * q], u = acc[mt][2 * q + 1];
            const int colI = col0 + wn * 32 + q * 16 + lr16;
            #pragma unroll
            for (int i = 0; i < 4; ++i) {
                int r = wm * 64 + mt * 16 + kc * 4 + i;
                if (r < ne) {
                    float s = sws[r];
                    short* dst = sh ? (acts + (size_t)(r0 + r) * IS_DIM + colI)
                                    : (act + ((size_t)e * CAP + r) * I_DIM + colI);
                    *dst = f2bf(s * silu_(g[i]) * u[i]);
                }
            }
        }
    }
}

// down-proj: shared rows store straight to out; routed rows store to compact yr.
// NO atomics.  grid (8, MAXTILES)
__global__ __launch_bounds__(512, 2) void down_all_kernel(
    const short* __restrict__ act, const short* __restrict__ acts,
    const float* __restrict__ w_down, const float* __restrict__ w_ds,
    const int* __restrict__ ntiles, const int* __restrict__ tiles,
    float* __restrict__ yr, float* __restrict__ out)
{
    if ((int)blockIdx.y >= *ntiles) return;
    const int e  = tiles[blockIdx.y * 4];
    const int r0 = tiles[blockIdx.y * 4 + 1];
    const int ne = tiles[blockIdx.y * 4 + 2];
    const int bo = tiles[blockIdx.y * 4 + 3];   // compact slot base for routed
    const bool sh = (e < 0);
    const int h0 = blockIdx.x * 128;
    const int mchunks = (ne + 63) >> 6;
    const int rows = mchunks << 6;

    __shared__ __align__(16) short As[2][256 * LDSTRIDE];
    __shared__ __align__(16) short Bs[2][128 * LDSTRIDE];

    const int tid = threadIdx.x;
    const int lane = tid & 63, wid = tid >> 6;
    const int wm = wid & 3, wn = wid >> 2;
    const int lr16 = lane & 15, kc = lane >> 4;
    const int sc_ = tid & 3, srow = tid >> 2;

    const int Kdim = sh ? IS_DIM : I_DIM;
    const short* abase = sh ? (acts + (size_t)r0 * IS_DIM) : (act + (size_t)e * CAP * I_DIM);
    const float* wbase = sh ? w_ds : (w_down + (size_t)e * H_DIM * I_DIM);
    const float* bptr  = wbase + (size_t)(h0 + srow) * Kdim + sc_ * 8;
    const bool a0v = srow < rows;
    const bool a1v = (srow + 128) < rows;
    const short* aptr0 = abase + (size_t)srow * Kdim + sc_ * 8;
    const short* aptr1 = abase + (size_t)(srow + 128) * Kdim + sc_ * 8;
    const int aoff0 = srow * LDSTRIDE + sc_ * 8;
    const int aoff1 = (srow + 128) * LDSTRIDE + sc_ * 8;
    const int boff  = srow * LDSTRIDE + sc_ * 8;

    f32x4 acc[4][4];
    #pragma unroll
    for (int i = 0; i < 4; ++i)
        #pragma unroll
        for (int j = 0; j < 4; ++j) acc[i][j] = 0.f;

    short8v cA0{}, cA1{};
    if (a0v) cA0 = *(const short8v*)(aptr0);
    if (a1v) cA1 = *(const short8v*)(aptr1);
    float4 cB0 = *(const float4*)(bptr), cB1 = *(const float4*)(bptr + 4);

    int buf = 0;
    for (int k0 = 0; k0 < Kdim; k0 += 32) {
        short8v nA0{}, nA1{};
        float4 nB0{}, nB1{};
        const int k1 = k0 + 32;
        if (k1 < Kdim) {
            if (a0v) nA0 = *(const short8v*)(aptr0 + k1);
            if (a1v) nA1 = *(const short8v*)(aptr1 + k1);
            nB0 = *(const float4*)(bptr + k1); nB1 = *(const float4*)(bptr + k1 + 4);
        }
        if (a0v) *(short8v*)&As[buf][aoff0] = cA0;
        if (a1v) *(short8v*)&As[buf][aoff1] = cA1;
        *(uint4v*)&Bs[buf][boff] = pk8bf(cB0, cB1);
        BAR_RELAXED();
        if (wm < mchunks) {
            short8v a_[4], b_[4];
            #pragma unroll
            for (int mt = 0; mt < 4; ++mt)
                a_[mt] = *(const short8v*)&As[buf][(wm * 64 + mt * 16 + lr16) * LDSTRIDE + kc * 8];
            #pragma unroll
            for (int nt = 0; nt < 4; ++nt)
                b_[nt] = *(const short8v*)&Bs[buf][(wn * 64 + nt * 16 + lr16) * LDSTRIDE + kc * 8];
            #pragma unroll
            for (int mt = 0; mt < 4; ++mt)
                #pragma unroll
                for (int nt = 0; nt < 4; ++nt)
                    acc[mt][nt] = __builtin_amdgcn_mfma_f32_16x16x32_bf16(a_[mt], b_[nt], acc[mt][nt], 0, 0, 0);
        }
        buf ^= 1;
        cA0 = nA0; cA1 = nA1; cB0 = nB0; cB1 = nB1;
    }

    if (wm >= mchunks) return;
    #pragma unroll
    for (int mt = 0; mt < 4; ++mt) {
        #pragma unroll
        for (int i = 0; i < 4; ++i) {
            int r = wm * 64 + mt * 16 + kc * 4 + i;
            if (r < ne) {
                float* orow = sh ? (out + (size_t)(r0 + r) * H_DIM + h0 + wn * 64)
                                 : (yr + (size_t)(bo + r) * H_DIM + h0 + wn * 64);
                #pragma unroll
                for (int nt = 0; nt < 4; ++nt)
                    orow[nt * 16 + lr16] = acc[mt][nt][i];
            }
        }
    }
}

// out[t] += sum over this token's kept routed slots.  grid T_TOK x 256
__global__ __launch_bounds__(256) void combine_kernel(
    const float* __restrict__ yr, const int* __restrict__ tok2slot,
    float* __restrict__ out)
{
    const int t = blockIdx.x, tid = threadIdx.x;
    float4 a = ((const float4*)(out + (size_t)t * H_DIM))[tid];
    #pragma unroll
    for (int k = 0; k < K_TOP; ++k) {
        int s = tok2slot[t * K_TOP + k];
        if (s >= 0) {
            float4 b = ((const float4*)(yr + (size_t)s * H_DIM))[tid];
            a.x += b.x; a.y += b.y; a.z += b.z; a.w += b.w;
        }
    }
    ((float4*)(out + (size_t)t * H_DIM))[tid] = a;
}

extern "C" void kernel_launch(void* const* d_in, const int* in_sizes, int n_in,
                              void* d_out, int out_size, void* d_ws, size_t ws_size,
                              hipStream_t stream) {
    const float* x   = (const float*)d_in[0];
    const float* gw  = (const float*)d_in[1];
    const float* eb  = (const float*)d_in[2];
    const float* wgu = (const float*)d_in[3];
    const float* wd  = (const float*)d_in[4];
    const float* wgs = (const float*)d_in[5];
    const float* wds = (const float*)d_in[6];
    float* out = (float*)d_out;
    char* ws = (char*)d_ws;

    int*   cnt    = (int*)(ws + WS_CNT_OFF);
    int*   ntiles = (int*)(ws + WS_NT_OFF);
    int*   tiles  = (int*)(ws + WS_TILE_OFF);
    int*   eidx   = (int*)(ws + WS_EIDX_OFF);
    float* wnorm  = (float*)(ws + WS_WN_OFF);
    int*   stok   = (int*)(ws + WS_STOK_OFF);
    float* sw     = (float*)(ws + WS_SW_OFF);
    short* act    = (short*)(ws + WS_ACT_OFF);
    short* acts   = (short*)(ws + WS_ACTS_OFF);
    short* xb     = (short*)(ws + WS_XB_OFF);
    int*   t2s    = (int*)(ws + WS_T2S_OFF);
    float* yr     = (float*)(ws + WS_YR_OFF);

    gate_kernel<<<T_TOK, 256, 0, stream>>>(x, gw, eb, eidx, wnorm, xb);
    assign_kernel<<<1, 256, 0, stream>>>(eidx, wnorm, cnt, stok, sw, ntiles, tiles, t2s);
    gu_all_kernel<<<dim3(IS_DIM / 64, MAXTILES), 512, 0, stream>>>(
        xb, wgu, wgs, ntiles, tiles, stok, sw, act, acts);
    down_all_kernel<<<dim3(H_DIM / 128, MAXTILES), 512, 0, stream>>>(
        act, acts, wd, wds, ntiles, tiles, yr, out);
    combine_kernel<<<T_TOK, 256, 0, stream>>>(yr, t2s, out);
}

// Round 5
// 400.502 us; speedup vs baseline: 1.1004x; 1.1004x over previous
//
#include <hip/hip_runtime.h>
#include <hip/hip_bf16.h>
#include <math.h>

// Problem constants (match reference)
#define T_TOK 1024
#define H_DIM 1024
#define I_DIM 512
#define E_NUM 32
#define K_TOP 4
#define G_NUM 8
#define TG_NUM 4
#define CAP 256              // C = 2*T*K/E
#define IS_DIM 1024          // I * NS
#define RSCALE 2.5f

#define MAXTILES 72          // 8 shared (128-row) + <=64 routed chunks (128-row)

// ws layout (byte offsets)
#define WS_CNT_OFF    0          // int cnt[32]
#define WS_NT_OFF     128        // int ntiles
#define WS_TILE_OFF   256        // int tiles[MAXTILES][4] = (e, r0, ne, boff)
#define WS_EIDX_OFF   4096       // int eidx[T*K]
#define WS_WN_OFF     20480      // float wnorm[T*K]
#define WS_STOK_OFF   36864      // int slot_token[E*CAP]
#define WS_SW_OFF     69632      // float slot_w[E*CAP]
#define WS_ACT_OFF    102400     // bf16 act[E*CAP*I]  (8 MB)
#define WS_ACTS_OFF   (102400 + (size_t)E_NUM*CAP*I_DIM*2)   // bf16 acts[T*IS] (2 MB)
#define WS_XB_OFF     (WS_ACTS_OFF + (size_t)T_TOK*IS_DIM*2) // bf16 xb[T*H]    (2 MB)
#define WS_T2S_OFF    (WS_XB_OFF + (size_t)T_TOK*H_DIM*2)    // int tok2slot[T*K] (16 KB)
#define WS_YR_OFF     (WS_T2S_OFF + (size_t)T_TOK*K_TOP*4)   // f32 yr[T*K][H] (16 MB)

typedef __attribute__((ext_vector_type(8))) short short8v;
typedef __attribute__((ext_vector_type(4))) float f32x4;
typedef __attribute__((ext_vector_type(4))) unsigned uint4v;

__device__ __forceinline__ short f2bf(float f) {          // RNE, epilogue only
    unsigned u = __float_as_uint(f);
    u += 0x7FFFu + ((u >> 16) & 1u);
    return (short)(u >> 16);
}
// pack 2 floats -> 2 bf16 (round-half-up): 3 VALU ops
__device__ __forceinline__ unsigned pk2bf(float a, float b) {
    unsigned ua = __float_as_uint(a) + 0x8000u;
    unsigned ub = __float_as_uint(b) + 0x8000u;
    return __builtin_amdgcn_perm(ub, ua, 0x07060302);      // lo short=bf(a), hi=bf(b)
}
__device__ __forceinline__ uint4v pk8bf(float4 lo, float4 hi) {
    uint4v r; r.x = pk2bf(lo.x, lo.y); r.y = pk2bf(lo.z, lo.w);
    r.z = pk2bf(hi.x, hi.y); r.w = pk2bf(hi.z, hi.w); return r;
}
__device__ __forceinline__ float silu_(float g) { return g / (1.f + expf(-g)); }

// Relaxed barrier: LDS-drain only, NO vmcnt(0) drain of in-flight prefetch.
#define BAR_RELAXED() do { \
    asm volatile("s_waitcnt lgkmcnt(0)" ::: "memory"); \
    __builtin_amdgcn_s_barrier(); \
    asm volatile("" ::: "memory"); \
} while (0)

#define LDSTRIDE 72   // shorts per LDS row for BK=64 (144 B, 16B-aligned b128 rows)

// -------- gating (also emits bf16 copy of x for GEMM A-operand) --------
__global__ __launch_bounds__(256) void gate_kernel(
    const float* __restrict__ x, const float* __restrict__ gate_w,
    const float* __restrict__ e_bias,
    int* __restrict__ eidx, float* __restrict__ wnorm, short* __restrict__ xb)
{
    __shared__ float xs[H_DIM];
    __shared__ float logits[E_NUM];
    const int t = blockIdx.x;
    const int tid = threadIdx.x;
    float4 v = ((const float4*)(x + (size_t)t * H_DIM))[tid];
    ((float4*)xs)[tid] = v;
    {   // bf16 copy of this token's row (same rounding as GEMM staging uses)
        unsigned* xd = (unsigned*)(xb + (size_t)t * H_DIM) + tid * 2;
        xd[0] = pk2bf(v.x, v.y); xd[1] = pk2bf(v.z, v.w);
    }
    __syncthreads();

    const int e = tid >> 3, sub = tid & 7;   // 32 experts x 8 threads
    const float4* gw4 = (const float4*)(gate_w + (size_t)e * H_DIM + sub * 128);
    const float4* xr4 = (const float4*)(xs + sub * 128);
    float p = 0.f;
    #pragma unroll
    for (int h = 0; h < 32; ++h) {
        float4 a = xr4[h], b = gw4[h];
        p += a.x * b.x + a.y * b.y + a.z * b.z + a.w * b.w;
    }
    for (int off = 4; off; off >>= 1) p += __shfl_down(p, off, 8);
    if (sub == 0) logits[e] = p;
    __syncthreads();
    if (tid != 0) return;

    float sc[E_NUM], sfc[E_NUM];
    for (int i = 0; i < E_NUM; ++i) {
        sc[i] = 1.f / (1.f + expf(-logits[i]));
        sfc[i] = sc[i] + e_bias[i];
    }
    float gs[G_NUM];
    for (int g = 0; g < G_NUM; ++g) {
        float m1 = -1e30f, m2 = -1e30f;
        for (int j = 0; j < E_NUM / G_NUM; ++j) {
            float v2 = sfc[g * (E_NUM / G_NUM) + j];
            if (v2 > m1) { m2 = m1; m1 = v2; } else if (v2 > m2) m2 = v2;
        }
        gs[g] = m1 + m2;
    }
    bool gm[G_NUM];
    for (int g = 0; g < G_NUM; ++g) gm[g] = false;
    for (int it = 0; it < TG_NUM; ++it) {
        int best = -1; float bv = -1e30f;
        for (int g = 0; g < G_NUM; ++g) if (!gm[g] && gs[g] > bv) { bv = gs[g]; best = g; }
        gm[best] = true;
    }
    float sm[E_NUM];
    for (int i = 0; i < E_NUM; ++i) sm[i] = gm[i / (E_NUM / G_NUM)] ? sfc[i] : 0.0f;
    int idx[K_TOP]; float w[K_TOP]; float tsum = 0.f;
    for (int it = 0; it < K_TOP; ++it) {
        int best = 0; float bv = -1e30f;
        for (int i = 0; i < E_NUM; ++i) if (sm[i] > bv) { bv = sm[i]; best = i; }
        sm[best] = -1e30f;
        idx[it] = best; w[it] = sc[best]; tsum += w[it];
    }
    float inv = RSCALE / (tsum + 1e-20f);
    const int base = t * K_TOP;
    for (int it = 0; it < K_TOP; ++it) {
        eidx[base + it] = idx[it];
        wnorm[base + it] = w[it] * inv;
    }
}

// ---- deterministic capacity dispatch + tile list + compact slot mapping ----
// tiles are now <=128-row chunks (M-tile of the GEMMs)
__global__ __launch_bounds__(256) void assign_kernel(
    const int* __restrict__ eidx, const float* __restrict__ wnorm,
    int* __restrict__ cnt, int* __restrict__ slot_token, float* __restrict__ slot_w,
    int* __restrict__ ntiles, int* __restrict__ tiles, int* __restrict__ tok2slot)
{
    __shared__ int   se[T_TOK * K_TOP];
    __shared__ float swt[T_TOK * K_TOP];
    __shared__ int   scnt[E_NUM];
    const int tid = threadIdx.x;
    for (int i = tid; i < T_TOK * K_TOP; i += 256) { se[i] = eidx[i]; swt[i] = wnorm[i]; }
    __syncthreads();

    const int e = tid >> 3;
    const int seg = tid & 7;
    const int base = seg * 512;
    int c = 0;
    for (int i = 0; i < 512; ++i) c += (se[base + i] == e);
    int excl = 0, total = 0;
    for (int s = 0; s < 8; ++s) {
        int cs = __shfl(c, s, 8);
        total += cs;
        if (s < seg) excl += cs;
    }
    if (seg == 0) { cnt[e] = total; scnt[e] = total; }
    __syncthreads();
    // compact base offset for this expert (sum of kept counts of lower experts)
    int boff = 0;
    for (int ee = 0; ee < e; ++ee) boff += min(scnt[ee], CAP);

    int pos = excl;
    for (int i = 0; i < 512; ++i) {
        if (se[base + i] == e) {
            const int g = base + i;
            if (pos < CAP) {
                slot_token[e * CAP + pos] = g >> 2;
                slot_w[e * CAP + pos] = swt[g];
                tok2slot[g] = boff + pos;
            } else {
                tok2slot[g] = -1;   // capacity-dropped (matches reference keep=0)
            }
            ++pos;
        }
    }
    __syncthreads();
    if (tid == 0) {
        int nt = 0;
        // shared-expert tiles first (128-row chunks)
        for (int t0 = 0; t0 < T_TOK; t0 += 128) {
            tiles[nt * 4] = -1; tiles[nt * 4 + 1] = t0; tiles[nt * 4 + 2] = 128;
            tiles[nt * 4 + 3] = 0; ++nt;
        }
        // routed: 128-row chunks per expert
        int off = 0;
        for (int ee = 0; ee < E_NUM; ++ee) {
            int n = min(scnt[ee], CAP);
            for (int r = 0; r < n; r += 128) {
                tiles[nt * 4] = ee; tiles[nt * 4 + 1] = r;
                tiles[nt * 4 + 2] = min(128, n - r);
                tiles[nt * 4 + 3] = off + r; ++nt;
            }
            off += n;
        }
        *ntiles = nt;
    }
}

// ---------------- MFMA GEMM: block tile 128(M) x 128(B-rows), BK=64, LDS dbuf --
// 512 threads = 8 waves: wm=wid&1 owns 64 M-rows, wn=wid>>1 owns 32 B-rows.
// 16 MFMA/wave/iter (2 k-substeps). Half the K-iterations of the BK=32 version.

// staging indices: sc_ = tid&7 (8-elem col chunk), srow = tid>>3 (0..63); rows srow, srow+64
#define GEMM_SETUP() \
    const int tid = threadIdx.x; \
    const int lane = tid & 63, wid = tid >> 6; \
    const int wm = wid & 1, wn = wid >> 1; \
    const int lr16 = lane & 15, kc = lane >> 4; \
    const int sc_ = tid & 7, srow = tid >> 3; \
    const int aoff0 = srow * LDSTRIDE + sc_ * 8; \
    const int aoff1 = (srow + 64) * LDSTRIDE + sc_ * 8;

#define DECL_ACC42() f32x4 acc[4][2]; \
    _Pragma("unroll") for (int i_ = 0; i_ < 4; ++i_) \
    _Pragma("unroll") for (int j_ = 0; j_ < 2; ++j_) acc[i_][j_] = 0.f;

#define COMPUTE_BK64(Asb, Bsb) do { \
    _Pragma("unroll") for (int ks = 0; ks < 2; ++ks) { \
        short8v a_[4], b_[2]; \
        _Pragma("unroll") for (int mt = 0; mt < 4; ++mt) \
            a_[mt] = *(const short8v*)&(Asb)[(wm*64 + mt*16 + lr16)*LDSTRIDE + ks*32 + kc*8]; \
        _Pragma("unroll") for (int nt = 0; nt < 2; ++nt) \
            b_[nt] = *(const short8v*)&(Bsb)[(wn*32 + nt*16 + lr16)*LDSTRIDE + ks*32 + kc*8]; \
        _Pragma("unroll") for (int mt = 0; mt < 4; ++mt) \
        _Pragma("unroll") for (int nt = 0; nt < 2; ++nt) \
            acc[mt][nt] = __builtin_amdgcn_mfma_f32_16x16x32_bf16(a_[mt], b_[nt], acc[mt][nt], 0, 0, 0); \
    } \
} while (0)

// gate_up + SiLU*mul for routed (+slot_w) AND shared experts. grid (16, MAXTILES)
__global__ __launch_bounds__(512, 4) void gu_all_kernel(
    const short* __restrict__ xb, const float* __restrict__ w_gate_up,
    const float* __restrict__ w_gus,
    const int* __restrict__ ntiles, const int* __restrict__ tiles,
    const int* __restrict__ slot_token, const float* __restrict__ slot_w,
    short* __restrict__ act, short* __restrict__ acts)
{
    if ((int)blockIdx.y >= *ntiles) return;
    const int e  = tiles[blockIdx.y * 4];
    const int r0 = tiles[blockIdx.y * 4 + 1];
    const int ne = tiles[blockIdx.y * 4 + 2];
    const bool sh = (e < 0);
    if (!sh && blockIdx.x >= I_DIM / 64) return;
    const int col0 = blockIdx.x * 64;

    __shared__ __align__(16) short As[2][128 * LDSTRIDE];
    __shared__ __align__(16) short Bs[2][128 * LDSTRIDE];
    __shared__ int   toks[128];
    __shared__ float sws[128];

    GEMM_SETUP();
    if (tid < 128) {
        if (sh) { toks[tid] = r0 + tid; sws[tid] = 1.f; }
        else {
            bool v = tid < ne;
            toks[tid] = v ? slot_token[e * CAP + r0 + tid] : 0;
            sws[tid]  = v ? slot_w[e * CAP + r0 + tid] : 0.f;
        }
    }
    __syncthreads();

    const int IDim = sh ? IS_DIM : I_DIM;
    const float* wbase = sh ? w_gus : (w_gate_up + (size_t)e * (2 * I_DIM) * H_DIM);
    // B-row r -> weight row: 16-row groups alternate gate/up so acc pairs line up
    const int r_0 = srow, r_1 = srow + 64;
    const int wr0 = ((r_0 >> 4) & 1) * IDim + col0 + ((r_0 >> 5) << 4) + (r_0 & 15);
    const int wr1 = ((r_1 >> 4) & 1) * IDim + col0 + ((r_1 >> 5) << 4) + (r_1 & 15);
    const float* bptr0 = wbase + (size_t)wr0 * H_DIM + sc_ * 8;
    const float* bptr1 = wbase + (size_t)wr1 * H_DIM + sc_ * 8;
    const short* aptr0 = xb + (size_t)toks[r_0] * H_DIM + sc_ * 8;
    const short* aptr1 = xb + (size_t)toks[r_1] * H_DIM + sc_ * 8;

    DECL_ACC42();
    short8v cA0 = *(const short8v*)(aptr0), cA1 = *(const short8v*)(aptr1);
    float4 cB0a = *(const float4*)(bptr0), cB0b = *(const float4*)(bptr0 + 4);
    float4 cB1a = *(const float4*)(bptr1), cB1b = *(const float4*)(bptr1 + 4);

    int buf = 0;
    for (int k0 = 0; k0 < H_DIM; k0 += 64) {
        short8v nA0{}, nA1{};
        float4 nB0a{}, nB0b{}, nB1a{}, nB1b{};
        const int k1 = k0 + 64;
        if (k1 < H_DIM) {
            nA0 = *(const short8v*)(aptr0 + k1);  nA1 = *(const short8v*)(aptr1 + k1);
            nB0a = *(const float4*)(bptr0 + k1);  nB0b = *(const float4*)(bptr0 + k1 + 4);
            nB1a = *(const float4*)(bptr1 + k1);  nB1b = *(const float4*)(bptr1 + k1 + 4);
        }
        *(short8v*)&As[buf][aoff0] = cA0;
        *(short8v*)&As[buf][aoff1] = cA1;
        *(uint4v*)&Bs[buf][aoff0]  = pk8bf(cB0a, cB0b);
        *(uint4v*)&Bs[buf][aoff1]  = pk8bf(cB1a, cB1b);
        BAR_RELAXED();
        COMPUTE_BK64(As[buf], Bs[buf]);
        buf ^= 1;
        cA0 = nA0; cA1 = nA1;
        cB0a = nB0a; cB0b = nB0b; cB1a = nB1a; cB1b = nB1b;
    }

    #pragma unroll
    for (int mt = 0; mt < 4; ++mt) {
        f32x4 g = acc[mt][0], u = acc[mt][1];
        const int colI = col0 + wn * 16 + lr16;
        #pragma unroll
        for (int i = 0; i < 4; ++i) {
            int r = wm * 64 + mt * 16 + kc * 4 + i;
            if (r < ne) {
                float s = sws[r];
                short* dst = sh ? (acts + (size_t)(r0 + r) * IS_DIM + colI)
                                : (act + ((size_t)e * CAP + r0 + r) * I_DIM + colI);
                *dst = f2bf(s * silu_(g[i]) * u[i]);
            }
        }
    }
}

// down-proj: shared rows store straight to out; routed rows store to compact yr.
// NO atomics.  grid (8, MAXTILES)
__global__ __launch_bounds__(512, 4) void down_all_kernel(
    const short* __restrict__ act, const short* __restrict__ acts,
    const float* __restrict__ w_down, const float* __restrict__ w_ds,
    const int* __restrict__ ntiles, const int* __restrict__ tiles,
    float* __restrict__ yr, float* __restrict__ out)
{
    if ((int)blockIdx.y >= *ntiles) return;
    const int e  = tiles[blockIdx.y * 4];
    const int r0 = tiles[blockIdx.y * 4 + 1];
    const int ne = tiles[blockIdx.y * 4 + 2];
    const int bo = tiles[blockIdx.y * 4 + 3];   // compact slot base for routed
    const bool sh = (e < 0);
    const int h0 = blockIdx.x * 128;

    __shared__ __align__(16) short As[2][128 * LDSTRIDE];
    __shared__ __align__(16) short Bs[2][128 * LDSTRIDE];

    GEMM_SETUP();

    const int Kdim = sh ? IS_DIM : I_DIM;
    const short* abase = sh ? (acts + (size_t)r0 * IS_DIM)
                            : (act + ((size_t)e * CAP + r0) * I_DIM);
    const float* wbase = sh ? w_ds : (w_down + (size_t)e * H_DIM * I_DIM);
    const float* bptr0 = wbase + (size_t)(h0 + srow) * Kdim + sc_ * 8;
    const float* bptr1 = wbase + (size_t)(h0 + srow + 64) * Kdim + sc_ * 8;
    const short* aptr0 = abase + (size_t)srow * Kdim + sc_ * 8;
    const short* aptr1 = abase + (size_t)(srow + 64) * Kdim + sc_ * 8;

    DECL_ACC42();
    short8v cA0 = *(const short8v*)(aptr0), cA1 = *(const short8v*)(aptr1);
    float4 cB0a = *(const float4*)(bptr0), cB0b = *(const float4*)(bptr0 + 4);
    float4 cB1a = *(const float4*)(bptr1), cB1b = *(const float4*)(bptr1 + 4);

    int buf = 0;
    for (int k0 = 0; k0 < Kdim; k0 += 64) {
        short8v nA0{}, nA1{};
        float4 nB0a{}, nB0b{}, nB1a{}, nB1b{};
        const int k1 = k0 + 64;
        if (k1 < Kdim) {
            nA0 = *(const short8v*)(aptr0 + k1);  nA1 = *(const short8v*)(aptr1 + k1);
            nB0a = *(const float4*)(bptr0 + k1);  nB0b = *(const float4*)(bptr0 + k1 + 4);
            nB1a = *(const float4*)(bptr1 + k1);  nB1b = *(const float4*)(bptr1 + k1 + 4);
        }
        *(short8v*)&As[buf][aoff0] = cA0;
        *(short8v*)&As[buf][aoff1] = cA1;
        *(uint4v*)&Bs[buf][aoff0]  = pk8bf(cB0a, cB0b);
        *(uint4v*)&Bs[buf][aoff1]  = pk8bf(cB1a, cB1b);
        BAR_RELAXED();
        COMPUTE_BK64(As[buf], Bs[buf]);
        buf ^= 1;
        cA0 = nA0; cA1 = nA1;
        cB0a = nB0a; cB0b = nB0b; cB1a = nB1a; cB1b = nB1b;
    }

    #pragma unroll
    for (int mt = 0; mt < 4; ++mt) {
        #pragma unroll
        for (int i = 0; i < 4; ++i) {
            int r = wm * 64 + mt * 16 + kc * 4 + i;
            if (r < ne) {
                float* orow = sh ? (out + (size_t)(r0 + r) * H_DIM + h0 + wn * 32)
                                 : (yr + (size_t)(bo + r) * H_DIM + h0 + wn * 32);
                #pragma unroll
                for (int nt = 0; nt < 2; ++nt)
                    orow[nt * 16 + lr16] = acc[mt][nt][i];
            }
        }
    }
}

// out[t] += sum over this token's kept routed slots.  grid T_TOK x 256
__global__ __launch_bounds__(256) void combine_kernel(
    const float* __restrict__ yr, const int* __restrict__ tok2slot,
    float* __restrict__ out)
{
    const int t = blockIdx.x, tid = threadIdx.x;
    float4 a = ((const float4*)(out + (size_t)t * H_DIM))[tid];
    #pragma unroll
    for (int k = 0; k < K_TOP; ++k) {
        int s = tok2slot[t * K_TOP + k];
        if (s >= 0) {
            float4 b = ((const float4*)(yr + (size_t)s * H_DIM))[tid];
            a.x += b.x; a.y += b.y; a.z += b.z; a.w += b.w;
        }
    }
    ((float4*)(out + (size_t)t * H_DIM))[tid] = a;
}

extern "C" void kernel_launch(void* const* d_in, const int* in_sizes, int n_in,
                              void* d_out, int out_size, void* d_ws, size_t ws_size,
                              hipStream_t stream) {
    const float* x   = (const float*)d_in[0];
    const float* gw  = (const float*)d_in[1];
    const float* eb  = (const float*)d_in[2];
    const float* wgu = (const float*)d_in[3];
    const float* wd  = (const float*)d_in[4];
    const float* wgs = (const float*)d_in[5];
    const float* wds = (const float*)d_in[6];
    float* out = (float*)d_out;
    char* ws = (char*)d_ws;

    int*   cnt    = (int*)(ws + WS_CNT_OFF);
    int*   ntiles = (int*)(ws + WS_NT_OFF);
    int*   tiles  = (int*)(ws + WS_TILE_OFF);
    int*   eidx   = (int*)(ws + WS_EIDX_OFF);
    float* wnorm  = (float*)(ws + WS_WN_OFF);
    int*   stok   = (int*)(ws + WS_STOK_OFF);
    float* sw     = (float*)(ws + WS_SW_OFF);
    short* act    = (short*)(ws + WS_ACT_OFF);
    short* acts   = (short*)(ws + WS_ACTS_OFF);
    short* xb     = (short*)(ws + WS_XB_OFF);
    int*   t2s    = (int*)(ws + WS_T2S_OFF);
    float* yr     = (float*)(ws + WS_YR_OFF);

    gate_kernel<<<T_TOK, 256, 0, stream>>>(x, gw, eb, eidx, wnorm, xb);
    assign_kernel<<<1, 256, 0, stream>>>(eidx, wnorm, cnt, stok, sw, ntiles, tiles, t2s);
    gu_all_kernel<<<dim3(IS_DIM / 64, MAXTILES), 512, 0, stream>>>(
        xb, wgu, wgs, ntiles, tiles, stok, sw, act, acts);
    down_all_kernel<<<dim3(H_DIM / 128, MAXTILES), 512, 0, stream>>>(
        act, acts, wd, wds, ntiles, tiles, yr, out);
    combine_kernel<<<T_TOK, 256, 0, stream>>>(yr, t2s, out);
}